// Round 2
// baseline (684.444 us; speedup 1.0000x reference)
//
#include <hip/hip_runtime.h>
#include <hip/hip_bf16.h>

typedef __bf16 bf16_t;
typedef __bf16 bf16x8 __attribute__((ext_vector_type(8)));
typedef float  f32x4  __attribute__((ext_vector_type(4)));

#define NB      32      // batch
#define NPIX    4096    // 64*64 pixels per sample
#define CIN     512
#define FOUT    512
#define TM      128
#define TN      128
#define BK      32

// async global->LDS, 16B per lane. LDS dest is wave-uniform base + lane*16.
__device__ __forceinline__ void async_copy16(const void* gsrc, void* ldsdst) {
    __builtin_amdgcn_global_load_lds(
        (const __attribute__((address_space(1))) unsigned int*)gsrc,
        (__attribute__((address_space(3))) unsigned int*)ldsdst,
        16, 0, 0);
}

// ---------------------------------------------------------------------------
// Pass 1: gather per-batch class weights, transpose [k][n] -> [n][k], cvt bf16.
// wsB[b][n][k] = (bf16) kernel[cls[b]][k][n]
// ---------------------------------------------------------------------------
__global__ __launch_bounds__(256) void gather_w_kernel(
    const float* __restrict__ kern, const int* __restrict__ cls,
    bf16_t* __restrict__ wsB)
{
    __shared__ float tile[32][33];
    const int n0 = blockIdx.x * 32;
    const int k0 = blockIdx.y * 32;
    const int b  = blockIdx.z;
    const int c  = cls[b];
    const int tx = threadIdx.x;      // 0..31
    const int ty = threadIdx.y;      // 0..7

    const float* src = kern + (long)c * CIN * FOUT;
#pragma unroll
    for (int i = 0; i < 4; i++) {
        int k = k0 + ty + i * 8;
        tile[ty + i * 8][tx] = src[(long)k * FOUT + n0 + tx];
    }
    __syncthreads();
    bf16_t* dst = wsB + (long)b * FOUT * CIN;
#pragma unroll
    for (int i = 0; i < 4; i++) {
        int n = n0 + ty + i * 8;
        dst[(long)n * CIN + k0 + tx] = (bf16_t)tile[tx][ty + i * 8];
    }
}

// ---------------------------------------------------------------------------
// Pass 2: per-batch GEMM. out[b,p,f] = sum_c x[b,p,c] * wsB[b,f,c] + bias[cls[b],f]
// - A (x, fp32): direct global->VGPR, 1-step software prefetch, cvt bf16 after
//   MFMA phase (VALU idle there). No LDS for A.
// - B (wsB, bf16): global_load_lds 16B, double-buffered, XOR-swizzled
//   (pre-swizzled source + swizzled ds_read), ONE barrier per K-step.
// - MFMA operands swapped so epilogue stores are dwordx4.
// ---------------------------------------------------------------------------
__global__ __launch_bounds__(256) void cond_conv_gemm(
    const float*  __restrict__ x,
    const bf16_t* __restrict__ wsB,
    const float*  __restrict__ bias,
    const int*    __restrict__ cls,
    float*        __restrict__ out)
{
    __shared__ bf16_t Bs[2][TN * BK];   // 2 x 8KB

    // XCD-chunked bijective swizzle: 4096 blocks, 512 logical per XCD.
    const int hw  = blockIdx.x;
    const int bid = (hw & 7) * 512 + (hw >> 3);

    const int n_t = bid & 3;            // fastest: 4 n-tiles share the A panel
    const int m_t = (bid >> 2) & 31;
    const int b   = bid >> 7;

    const long x_base = (long)b * NPIX * CIN + (long)m_t * TM * CIN;
    const long w_base = (long)b * FOUT * CIN;
    const int  n0     = n_t * TN;

    const int t    = threadIdx.x;
    const int wave = t >> 6;
    const int lane = t & 63;
    const int wm   = (wave >> 1) * 64;
    const int wn   = (wave & 1) * 64;
    const int l15  = lane & 15;
    const int quad = lane >> 4;

    // B staging lane coords: physical slot p=lane&3 of row n; row n&3 == (lane>>2)&3.
    // Fetch logical slot s = p ^ (n&3) (involution; read applies same XOR).
    const int b_row_in_g = wave * 16 + (lane >> 2);               // + g*64
    const int b_kc       = ((lane & 3) ^ ((lane >> 2) & 3)) << 3; // bf16 offset

    // A per-lane row pointers (row = wm + i*16 + l15, k-slice = quad*8)
    const float* a_ptr[4];
#pragma unroll
    for (int i = 0; i < 4; i++)
        a_ptr[i] = x + x_base + (long)(wm + i * 16 + l15) * CIN + quad * 8;

    f32x4 acc[4][4];
#pragma unroll
    for (int i = 0; i < 4; i++)
#pragma unroll
        for (int j = 0; j < 4; j++)
            acc[i][j] = (f32x4){0.f, 0.f, 0.f, 0.f};

    // ---- prologue: stage B(k=0) into buf0; load+cvt A(k=0) ----
#pragma unroll
    for (int g = 0; g < 2; g++)
        async_copy16(wsB + w_base + (long)(n0 + g * 64 + b_row_in_g) * CIN + b_kc,
                     (char*)(&Bs[0][0]) + g * 4096 + wave * 1024);
    bf16x8 af[4];
#pragma unroll
    for (int i = 0; i < 4; i++) {
        f32x4 lo = *(const f32x4*)(a_ptr[i]);
        f32x4 hi = *(const f32x4*)(a_ptr[i] + 4);
        bf16x8 h;
        h[0] = (bf16_t)lo[0]; h[1] = (bf16_t)lo[1];
        h[2] = (bf16_t)lo[2]; h[3] = (bf16_t)lo[3];
        h[4] = (bf16_t)hi[0]; h[5] = (bf16_t)hi[1];
        h[6] = (bf16_t)hi[2]; h[7] = (bf16_t)hi[3];
        af[i] = h;
    }
    __syncthreads();   // buf0 staged

    int cur = 0;
    for (int k0 = 0; k0 < CIN; k0 += BK) {
        const int  kn       = k0 + BK;
        const bool has_next = (kn < CIN);

        // 1) issue next B stage into the other buffer
        if (has_next) {
#pragma unroll
            for (int g = 0; g < 2; g++)
                async_copy16(wsB + w_base + (long)(n0 + g * 64 + b_row_in_g) * CIN + kn + b_kc,
                             (char*)(&Bs[cur ^ 1][0]) + g * 4096 + wave * 1024);
        }
        // 2) issue next A loads (land during MFMA phase)
        f32x4 n_lo[4], n_hi[4];
        if (has_next) {
#pragma unroll
            for (int i = 0; i < 4; i++) {
                n_lo[i] = *(const f32x4*)(a_ptr[i] + kn);
                n_hi[i] = *(const f32x4*)(a_ptr[i] + kn + 4);
            }
        }

        // 3) B fragments from current buffer (swizzled read)
        bf16x8 bfr[4];
#pragma unroll
        for (int i = 0; i < 4; i++) {
            int row = wn + i * 16 + l15;
            bfr[i] = *(const bf16x8*)(&Bs[cur][row * BK + ((quad ^ (row & 3)) << 3)]);
        }

        // 4) MFMA — operands swapped: D[n-dim][m-dim], rows=quad*4+r (n), cols=l15 (m)
#pragma unroll
        for (int mi = 0; mi < 4; mi++)
#pragma unroll
            for (int ni = 0; ni < 4; ni++)
                acc[mi][ni] = __builtin_amdgcn_mfma_f32_16x16x32_bf16(
                    bfr[ni], af[mi], acc[mi][ni], 0, 0, 0);

        // 5) convert next A (VALU idle post-MFMA; loads have had the MFMA phase to land)
        if (has_next) {
#pragma unroll
            for (int i = 0; i < 4; i++) {
                bf16x8 h;
                h[0] = (bf16_t)n_lo[i][0]; h[1] = (bf16_t)n_lo[i][1];
                h[2] = (bf16_t)n_lo[i][2]; h[3] = (bf16_t)n_lo[i][3];
                h[4] = (bf16_t)n_hi[i][0]; h[5] = (bf16_t)n_hi[i][1];
                h[6] = (bf16_t)n_hi[i][2]; h[7] = (bf16_t)n_hi[i][3];
                af[i] = h;
            }
        }

        __syncthreads();   // drains async B stage -> next buffer ready
        cur ^= 1;
    }

    // ---- epilogue: lane holds 4 consecutive n at one m -> dwordx4 stores ----
    const int  c        = cls[b];
    const long out_row0 = (long)b * NPIX * FOUT + (long)(m_t * TM) * FOUT + n0;
#pragma unroll
    for (int ni = 0; ni < 4; ni++) {
        f32x4 bv = *(const f32x4*)(&bias[(long)c * FOUT + n0 + wn + ni * 16 + quad * 4]);
#pragma unroll
        for (int mi = 0; mi < 4; mi++) {
            int m = wm + mi * 16 + l15;
            f32x4 v = acc[mi][ni] + bv;
            *(f32x4*)(&out[out_row0 + (long)m * FOUT + wn + ni * 16 + quad * 4]) = v;
        }
    }
}

// ---------------------------------------------------------------------------
// Fallback (only if ws too small): naive fp32, correct but slow.
// ---------------------------------------------------------------------------
__global__ __launch_bounds__(256) void naive_kernel(
    const float* __restrict__ x, const float* __restrict__ kern,
    const float* __restrict__ bias, const int* __restrict__ cls,
    float* __restrict__ out)
{
    long i = (long)blockIdx.x * 256 + threadIdx.x;
    if (i >= (long)NB * NPIX * FOUT) return;
    int f = (int)(i % FOUT);
    long p = i / FOUT;
    int b = (int)(p / NPIX);
    int c = cls[b];
    const float* xr = x + p * CIN;
    const float* wc = kern + (long)c * CIN * FOUT + f;
    float acc = 0.f;
    for (int k = 0; k < CIN; k++) acc += xr[k] * wc[(long)k * FOUT];
    out[i] = acc + bias[(long)c * FOUT + f];
}

extern "C" void kernel_launch(void* const* d_in, const int* in_sizes, int n_in,
                              void* d_out, int out_size, void* d_ws, size_t ws_size,
                              hipStream_t stream)
{
    const float* x    = (const float*)d_in[0];
    const int*   cls  = (const int*)d_in[1];
    const float* kern = (const float*)d_in[2];
    const float* bias = (const float*)d_in[3];
    float*       out  = (float*)d_out;

    const size_t ws_need = (size_t)NB * FOUT * CIN * sizeof(bf16_t);  // 16.8 MB
    if (ws_size >= ws_need) {
        bf16_t* wsB = (bf16_t*)d_ws;
        gather_w_kernel<<<dim3(FOUT / 32, CIN / 32, NB), dim3(32, 8), 0, stream>>>(
            kern, cls, wsB);
        cond_conv_gemm<<<NB * (NPIX / TM) * (FOUT / TN), 256, 0, stream>>>(
            x, wsB, bias, cls, out);
    } else {
        long n = (long)NB * NPIX * FOUT;
        naive_kernel<<<(int)((n + 255) / 256), 256, 0, stream>>>(x, kern, bias, cls, out);
    }
}

// Round 3
// 652.918 us; speedup vs baseline: 1.0483x; 1.0483x over previous
//
#include <hip/hip_runtime.h>
#include <hip/hip_bf16.h>

typedef __bf16 bf16_t;
typedef __bf16 bf16x4 __attribute__((ext_vector_type(4)));
typedef __bf16 bf16x8 __attribute__((ext_vector_type(8)));
typedef float  f32x4  __attribute__((ext_vector_type(4)));

#define NB      32      // batch
#define NPIX    4096    // 64*64 pixels per sample
#define CIN     512
#define FOUT    512
#define TM      128
#define TN      128
#define BK      32

// async global->LDS, 16B per lane. LDS dest is wave-uniform base + lane*16.
__device__ __forceinline__ void async_copy16(const void* gsrc, void* ldsdst) {
    __builtin_amdgcn_global_load_lds(
        (const __attribute__((address_space(1))) unsigned int*)gsrc,
        (__attribute__((address_space(3))) unsigned int*)ldsdst,
        16, 0, 0);
}

// ---------------------------------------------------------------------------
// Pass 0: convert x fp32 -> bf16 (memory-bound, ~65 us). 8 elems/thread/iter.
// ---------------------------------------------------------------------------
__global__ __launch_bounds__(256) void cvt_x_kernel(
    const float* __restrict__ x, bf16_t* __restrict__ xb)
{
    const long n8 = (long)NB * NPIX * CIN / 8;   // 8.39M groups of 8
    long i = (long)blockIdx.x * 256 + threadIdx.x;
    const long stride = (long)gridDim.x * 256;
    for (; i < n8; i += stride) {
        const float* s = x + i * 8;
        f32x4 lo = *(const f32x4*)(s);
        f32x4 hi = *(const f32x4*)(s + 4);
        bf16x8 h;
        h[0] = (bf16_t)lo[0]; h[1] = (bf16_t)lo[1];
        h[2] = (bf16_t)lo[2]; h[3] = (bf16_t)lo[3];
        h[4] = (bf16_t)hi[0]; h[5] = (bf16_t)hi[1];
        h[6] = (bf16_t)hi[2]; h[7] = (bf16_t)hi[3];
        *(bf16x8*)(xb + i * 8) = h;
    }
}

// ---------------------------------------------------------------------------
// Pass 1: gather per-batch class weights, transpose [k][n] -> [n][k], cvt bf16.
// wsB[b][n][k] = (bf16) kernel[cls[b]][k][n]
// ---------------------------------------------------------------------------
__global__ __launch_bounds__(256) void gather_w_kernel(
    const float* __restrict__ kern, const int* __restrict__ cls,
    bf16_t* __restrict__ wsB)
{
    __shared__ float tile[32][33];
    const int n0 = blockIdx.x * 32;
    const int k0 = blockIdx.y * 32;
    const int b  = blockIdx.z;
    const int c  = cls[b];
    const int tx = threadIdx.x;      // 0..31
    const int ty = threadIdx.y;      // 0..7

    const float* src = kern + (long)c * CIN * FOUT;
#pragma unroll
    for (int i = 0; i < 4; i++) {
        int k = k0 + ty + i * 8;
        tile[ty + i * 8][tx] = src[(long)k * FOUT + n0 + tx];
    }
    __syncthreads();
    bf16_t* dst = wsB + (long)b * FOUT * CIN;
#pragma unroll
    for (int i = 0; i < 4; i++) {
        int n = n0 + ty + i * 8;
        dst[(long)n * CIN + k0 + tx] = (bf16_t)tile[tx][ty + i * 8];
    }
}

// ---------------------------------------------------------------------------
// Pass 2 (tier 1): all-bf16 m97-structure GEMM.
// out[b,p,f] = sum_c xb[b,p,c] * wsB[b,f,c] + bias[cls[b],f]
// 128x128 tile, BK=32, global_load_lds(16B) both operands, 2 barriers/K-step.
// LDS rotation-swizzle: physical 16B slot p = (quad + row + (row>>2)) & 3
//   -> each quad-group's 16 rows hit all eight 4-bank groups exactly twice
//   (conflict floor). Staging fetches logical slice (p - f(row)) & 3 so the
//   linear global_load_lds write lands pre-swizzled (Guideline 21).
// MFMA operands swapped (D[n][m]) so epilogue stores are dwordx4.
// ---------------------------------------------------------------------------
__global__ __launch_bounds__(256) void cond_conv_gemm_bf16(
    const bf16_t* __restrict__ xb,
    const bf16_t* __restrict__ wsB,
    const float*  __restrict__ bias,
    const int*    __restrict__ cls,
    float*        __restrict__ out)
{
    __shared__ bf16_t As[TM * BK];   // 8 KB
    __shared__ bf16_t Bs[TN * BK];   // 8 KB

    // XCD-chunked bijective swizzle: 4096 blocks, 512 logical per XCD.
    const int hw  = blockIdx.x;
    const int bid = (hw & 7) * 512 + (hw >> 3);

    const int n_t = bid & 3;            // fastest: 4 n-tiles share the A panel
    const int m_t = (bid >> 2) & 31;
    const int b   = bid >> 7;

    const long a_base = (long)b * NPIX * CIN + (long)m_t * TM * CIN;
    const long w_base = (long)b * FOUT * CIN;
    const int  n0     = n_t * TN;

    const int t    = threadIdx.x;
    const int wave = t >> 6;
    const int lane = t & 63;
    const int wm   = (wave >> 1) * 64;
    const int wn   = (wave & 1) * 64;
    const int l15  = lane & 15;
    const int quad = lane >> 4;

    // staging coords: issue g covers rows g*64 + (t>>2); lane's physical slot t&3
    const int st_row = t >> 2;   // + g*64
    const int st_p   = t & 3;

    f32x4 acc[4][4];
#pragma unroll
    for (int i = 0; i < 4; i++)
#pragma unroll
        for (int j = 0; j < 4; j++)
            acc[i][j] = (f32x4){0.f, 0.f, 0.f, 0.f};

    // precompute per-lane staged k-slice offsets (constant over K-loop)
    int a_off[2];
#pragma unroll
    for (int g = 0; g < 2; g++) {
        int row = g * 64 + st_row;
        int f   = (row + (row >> 2)) & 3;
        a_off[g] = ((st_p - f) & 3) * 8;     // logical bf16 k-offset fetched
    }

    for (int k0 = 0; k0 < CIN; k0 += BK) {
#pragma unroll
        for (int g = 0; g < 2; g++) {
            int row = g * 64 + st_row;
            async_copy16(xb + a_base + (long)row * CIN + k0 + a_off[g],
                         (char*)As + g * 4096 + wave * 1024);
            async_copy16(wsB + w_base + (long)(n0 + row) * CIN + k0 + a_off[g],
                         (char*)Bs + g * 4096 + wave * 1024);
        }
        __syncthreads();   // drains vmcnt -> tiles visible

        bf16x8 af[4], bfr[4];
#pragma unroll
        for (int i = 0; i < 4; i++) {
            int row = wm + i * 16 + l15;
            int p   = (quad + row + (row >> 2)) & 3;
            af[i] = *(const bf16x8*)(&As[row * BK + p * 8]);
        }
#pragma unroll
        for (int i = 0; i < 4; i++) {
            int row = wn + i * 16 + l15;
            int p   = (quad + row + (row >> 2)) & 3;
            bfr[i] = *(const bf16x8*)(&Bs[row * BK + p * 8]);
        }
#pragma unroll
        for (int mi = 0; mi < 4; mi++)
#pragma unroll
            for (int ni = 0; ni < 4; ni++)
                acc[mi][ni] = __builtin_amdgcn_mfma_f32_16x16x32_bf16(
                    bfr[ni], af[mi], acc[mi][ni], 0, 0, 0);
        __syncthreads();
    }

    // epilogue: lane holds 4 consecutive n at one m -> dwordx4 stores
    const int  c        = cls[b];
    const long out_row0 = (long)b * NPIX * FOUT + (long)(m_t * TM) * FOUT + n0;
#pragma unroll
    for (int ni = 0; ni < 4; ni++) {
        f32x4 bv = *(const f32x4*)(&bias[(long)c * FOUT + n0 + wn + ni * 16 + quad * 4]);
#pragma unroll
        for (int mi = 0; mi < 4; mi++) {
            int m = wm + mi * 16 + l15;
            f32x4 v = acc[mi][ni] + bv;
            *(f32x4*)(&out[out_row0 + (long)m * FOUT + wn + ni * 16 + quad * 4]) = v;
        }
    }
}

// ---------------------------------------------------------------------------
// Pass 2 (tier 2, ws only fits wsB): round-1 mixed kernel (fp32 A via
// global_load_lds, measured 243 us). Kept as fallback.
// ---------------------------------------------------------------------------
__global__ __launch_bounds__(256) void cond_conv_gemm_mixed(
    const float*  __restrict__ x,
    const bf16_t* __restrict__ wsB,
    const float*  __restrict__ bias,
    const int*    __restrict__ cls,
    float*        __restrict__ out)
{
    __shared__ float  AsF[TM * BK];
    __shared__ bf16_t BsH[TN * BK];

    const int hw  = blockIdx.x;
    const int bid = (hw & 7) * 512 + (hw >> 3);
    const int n_t = bid & 3;
    const int m_t = (bid >> 2) & 31;
    const int b   = bid >> 7;

    const long x_base = (long)b * NPIX * CIN + (long)m_t * TM * CIN;
    const long w_base = (long)b * FOUT * CIN;
    const int  n0     = n_t * TN;

    const int t    = threadIdx.x;
    const int wave = t >> 6;
    const int lane = t & 63;
    const int wm   = (wave >> 1) * 64;
    const int wn   = (wave & 1) * 64;
    const int l15  = lane & 15;
    const int quad = lane >> 4;

    f32x4 acc[4][4];
#pragma unroll
    for (int i = 0; i < 4; i++)
#pragma unroll
        for (int j = 0; j < 4; j++)
            acc[i][j] = (f32x4){0.f, 0.f, 0.f, 0.f};

    const int a_row_in_g = wave * 8 + (lane >> 3);
    const int a_kc       = ((lane & 7) ^ (lane >> 3)) << 2;
    const int b_row_in_g = wave * 16 + (lane >> 2);
    const int b_kc       = ((lane & 3) ^ ((lane >> 2) & 3)) << 3;

    for (int k0 = 0; k0 < CIN; k0 += BK) {
#pragma unroll
        for (int g = 0; g < 4; g++)
            async_copy16(x + x_base + (long)(g * 32 + a_row_in_g) * CIN + k0 + a_kc,
                         (char*)AsF + g * 4096 + wave * 1024);
#pragma unroll
        for (int g = 0; g < 2; g++)
            async_copy16(wsB + w_base + (long)(n0 + g * 64 + b_row_in_g) * CIN + k0 + b_kc,
                         (char*)BsH + g * 4096 + wave * 1024);
        __syncthreads();

        bf16x8 af[4], bfr[4];
#pragma unroll
        for (int i = 0; i < 4; i++) {
            int row = wm + i * 16 + l15;
            int r7  = row & 7;
            f32x4 a0 = *(const f32x4*)(&AsF[row * BK + (((2 * quad)     ^ r7) << 2)]);
            f32x4 a1 = *(const f32x4*)(&AsF[row * BK + (((2 * quad + 1) ^ r7) << 2)]);
            bf16x8 h;
            h[0] = (bf16_t)a0[0]; h[1] = (bf16_t)a0[1];
            h[2] = (bf16_t)a0[2]; h[3] = (bf16_t)a0[3];
            h[4] = (bf16_t)a1[0]; h[5] = (bf16_t)a1[1];
            h[6] = (bf16_t)a1[2]; h[7] = (bf16_t)a1[3];
            af[i] = h;
        }
#pragma unroll
        for (int i = 0; i < 4; i++) {
            int row = wn + i * 16 + l15;
            bfr[i] = *(const bf16x8*)(&BsH[row * BK + ((quad ^ (row & 3)) << 3)]);
        }
#pragma unroll
        for (int mi = 0; mi < 4; mi++)
#pragma unroll
            for (int ni = 0; ni < 4; ni++)
                acc[mi][ni] = __builtin_amdgcn_mfma_f32_16x16x32_bf16(
                    bfr[ni], af[mi], acc[mi][ni], 0, 0, 0);
        __syncthreads();
    }

    const int  c        = cls[b];
    const long out_row0 = (long)b * NPIX * FOUT + (long)(m_t * TM) * FOUT + n0;
#pragma unroll
    for (int ni = 0; ni < 4; ni++) {
        f32x4 bv = *(const f32x4*)(&bias[(long)c * FOUT + n0 + wn + ni * 16 + quad * 4]);
#pragma unroll
        for (int mi = 0; mi < 4; mi++) {
            int m = wm + mi * 16 + l15;
            f32x4 v = acc[mi][ni] + bv;
            *(f32x4*)(&out[out_row0 + (long)m * FOUT + wn + ni * 16 + quad * 4]) = v;
        }
    }
}

// ---------------------------------------------------------------------------
// Fallback (ws too small for anything): naive fp32.
// ---------------------------------------------------------------------------
__global__ __launch_bounds__(256) void naive_kernel(
    const float* __restrict__ x, const float* __restrict__ kern,
    const float* __restrict__ bias, const int* __restrict__ cls,
    float* __restrict__ out)
{
    long i = (long)blockIdx.x * 256 + threadIdx.x;
    if (i >= (long)NB * NPIX * FOUT) return;
    int f = (int)(i % FOUT);
    long p = i / FOUT;
    int b = (int)(p / NPIX);
    int c = cls[b];
    const float* xr = x + p * CIN;
    const float* wc = kern + (long)c * CIN * FOUT + f;
    float acc = 0.f;
    for (int k = 0; k < CIN; k++) acc += xr[k] * wc[(long)k * FOUT];
    out[i] = acc + bias[(long)c * FOUT + f];
}

extern "C" void kernel_launch(void* const* d_in, const int* in_sizes, int n_in,
                              void* d_out, int out_size, void* d_ws, size_t ws_size,
                              hipStream_t stream)
{
    const float* x    = (const float*)d_in[0];
    const int*   cls  = (const int*)d_in[1];
    const float* kern = (const float*)d_in[2];
    const float* bias = (const float*)d_in[3];
    float*       out  = (float*)d_out;

    const size_t xb_bytes = (size_t)NB * NPIX * CIN * sizeof(bf16_t);  // 134.2 MB
    const size_t w_bytes  = (size_t)NB * FOUT * CIN * sizeof(bf16_t);  // 16.8 MB

    if (ws_size >= xb_bytes + w_bytes) {
        bf16_t* xbf = (bf16_t*)d_ws;
        bf16_t* wsB = xbf + (size_t)NB * NPIX * CIN;
        cvt_x_kernel<<<2048, 256, 0, stream>>>(x, xbf);
        gather_w_kernel<<<dim3(FOUT / 32, CIN / 32, NB), dim3(32, 8), 0, stream>>>(
            kern, cls, wsB);
        cond_conv_gemm_bf16<<<NB * (NPIX / TM) * (FOUT / TN), 256, 0, stream>>>(
            xbf, wsB, bias, cls, out);
    } else if (ws_size >= w_bytes) {
        bf16_t* wsB = (bf16_t*)d_ws;
        gather_w_kernel<<<dim3(FOUT / 32, CIN / 32, NB), dim3(32, 8), 0, stream>>>(
            kern, cls, wsB);
        cond_conv_gemm_mixed<<<NB * (NPIX / TM) * (FOUT / TN), 256, 0, stream>>>(
            x, wsB, bias, cls, out);
    } else {
        long n = (long)NB * NPIX * FOUT;
        naive_kernel<<<(int)((n + 255) / 256), 256, 0, stream>>>(x, kern, bias, cls, out);
    }
}